// Round 1
// baseline (304.088 us; speedup 1.0000x reference)
//
#include <hip/hip_runtime.h>
#include <hip/hip_fp16.h>

// ---------------------------------------------------------------------------
// SoftDecisionTreeEnsemble: N_TREES=15, DEPTH=3, INPUT_DIM=128, N_CLASSES=10
// R3: single-dispatch + de-serialize. Changes vs R2 (204.3us):
//  1. prep merged into tree_main: each block materializes bf/bb/wbf registers
//     straight from params (one-time, hides the primed DMA latency). No d_ws,
//     no second dispatch, no inter-kernel gap.
//  2. counted vmcnt(4) at tile top (peeled i==0): the 8 DMA loads are the
//     oldest outstanding vm-ops, so the previous tile's 4 out-stores no
//     longer serialize each tile (T4: never drain vmcnt to 0 in the loop).
//  3. Phase B: 28x ds_read_u16 (8-way bank conflict) -> 4x ds_read_b128
//     (RSTR=272=17*16: 16B-aligned, 8 lanes/16B-column = b128 optimum).
//  4. bias folded into MFMA accumulator init (kills 112 v_add per tile-lane).
// ---------------------------------------------------------------------------

typedef float    f32x4 __attribute__((ext_vector_type(4)));
typedef _Float16 half8 __attribute__((ext_vector_type(8)));

#define TREES      15
#define IDIM       128
#define NCLS       10
#define NINT       7
#define NLVS       8
#define PER_TREE   (NINT*IDIM + NINT + NLVS*NCLS)   // 983
#define NODES      (TREES*NINT)                     // 105
#define RSTR       272                              // s/leaf row stride bytes (136 halves)
#define NBLK       512                              // 2 blocks/CU

// DMA one wave-quarter (16 rows x 512B) of an x tile into LDS, with per-row
// 16B-chunk rotation: row r chunk c16 stored at slot (c16 + r) & 31.
// LDS dest of global_load_lds is wave-uniform base + lane*16 (lane-linear),
// so the swizzle is applied on the *global source* side.
__device__ __forceinline__ void dma_quarter(const float* __restrict__ x,
                                            long grow0, char* qdst, int lane) {
    const int slot = lane & 31;
    #pragma unroll
    for (int it = 0; it < 8; ++it) {
        int r   = 2 * it + (lane >> 5);
        int c16 = (slot - r) & 31;
        const float* gp = x + (grow0 + r) * IDIM + c16 * 4;
        __builtin_amdgcn_global_load_lds(
            (const __attribute__((address_space(1))) void*)gp,
            (__attribute__((address_space(3))) void*)(qdst + it * 1024),
            16, 0, 0);
    }
}

// ---------------------------------------------------------------------------
__global__ __launch_bounds__(256, 2) void tree_main(const float* __restrict__ x,
                                                    const float* __restrict__ p,
                                                    float* __restrict__ out,
                                                    int tpb) {
    __shared__ __align__(16) char lds[2][32768];

    const int tid  = threadIdx.x;
    const int lane = tid & 63;
    const int w    = tid >> 6;        // wave id: owns rows 16w..16w+15 of tile
    const int lm   = lane & 15;
    const int lq   = lane >> 4;
    const int rg   = lane >> 2;       // Phase B row (0..15)
    const int g    = lane & 3;        // Phase B tree group

    const long tile0 = (long)blockIdx.x * tpb;

    // prime the pipeline: DMA tile 0 (latency hides under weight materialize)
    dma_quarter(x, tile0 * 64 + 16 * w, &lds[0][w * 8192], lane);

    // ---- one-time per-block weight materialization (replaces prep kernel) --
    // bf[nt][s]: B-frag for z-GEMM; row g=16nt+lm of the zero-padded [112][128]
    // weight matrix, cols 32s+8lq..+7. Zero padding is load-bearing: padded
    // nodes give z=0 -> sigmoid 0.5; padded leaf cols/classes contribute 0.
    half8 bf[7][4];
    float bb[7];
    #pragma unroll
    for (int nt = 0; nt < 7; ++nt) {
        const int   node = 16 * nt + lm;
        const float sc   = (node < NODES) ? 1.f : 0.f;
        const int   nd   = (node < NODES) ? node : 0;
        const int   t    = (nd * 9363) >> 16;      // nd/7 (exact for nd<=110)
        const int   n    = nd - 7 * t;
        const float* wp  = p + t * PER_TREE + n * IDIM + 8 * lq;
        #pragma unroll
        for (int s = 0; s < 4; ++s) {
            half8 h;
            #pragma unroll
            for (int j = 0; j < 8; ++j)
                h[j] = (_Float16)(sc * wp[32 * s + j]);
            bf[nt][s] = h;
        }
        bb[nt] = sc * p[t * PER_TREE + NINT * IDIM + n];
    }

    // wbf[s]: B-frag for the leaf->class GEMM. Col k=32s+8lq+j maps to
    // (tree t=4s+lq, leaf l=j); value = softmax_c(leaf_logits[t][l])[lm]*tw[t].
    const float* tl = p + TREES * PER_TREE;
    float m2 = tl[0];
    #pragma unroll
    for (int j = 1; j < TREES; ++j) m2 = fmaxf(m2, tl[j]);
    float s2 = 0.f;
    #pragma unroll
    for (int j = 0; j < TREES; ++j) s2 += __expf(tl[j] - m2);

    half8 wbf[4];
    #pragma unroll
    for (int s = 0; s < 4; ++s) {
        const int   t     = 4 * s + lq;
        const int   tc    = (t < TREES) ? t : 0;
        const float tmask = (t < TREES) ? 1.f : 0.f;
        const float tw    = tmask * (__expf(tl[tc] - m2) / s2);
        const int   cc    = (lm < NCLS) ? lm : 0;
        const float cmask = (lm < NCLS) ? 1.f : 0.f;
        const float* lb   = p + tc * PER_TREE + NINT * IDIM + NINT;
        half8 hh;
        #pragma unroll
        for (int l = 0; l < NLVS; ++l) {
            const float* ll = lb + l * NCLS;
            float mx = ll[0];
            #pragma unroll
            for (int j = 1; j < NCLS; ++j) mx = fmaxf(mx, ll[j]);
            float se = 0.f;
            #pragma unroll
            for (int j = 0; j < NCLS; ++j) se += __expf(ll[j] - mx);
            float lsm = __expf(ll[cc] - mx) / se;
            hh[l] = (_Float16)(lsm * tw * cmask);
        }
        wbf[s] = hh;
    }

    // ---- main loop ---------------------------------------------------------
    for (int i = 0; i < tpb; ++i) {
        char* qcur = &lds[i & 1][w * 8192];
        const long grow = (tile0 + i) * 64;      // global row of this tile

        // wait for own DMA (wave-private; no barrier needed).
        // i==0: vmcnt(0) (only the 8 primed loads are in flight).
        // i>=1: vmcnt(4) — outstanding = 8 loads(tile i) then 4 stores(i-1);
        //       waiting to <=4 retires the loads, lets store-acks fly (T4).
        asm volatile("" ::: "memory");
        if (i == 0) __builtin_amdgcn_s_waitcnt(0x0F70);
        else        __builtin_amdgcn_s_waitcnt(0x0F74);
        asm volatile("" ::: "memory");

        // ---- A-fragment gather from swizzled LDS + cvt to f16 ----
        half8 af[4];
        #pragma unroll
        for (int s = 0; s < 4; ++s) {
            int cc = 8 * s + 2 * lq;
            f32x4 f0 = *(const f32x4*)(qcur + lm * 512 + (((cc     + lm) & 31) << 4));
            f32x4 f1 = *(const f32x4*)(qcur + lm * 512 + (((cc + 1 + lm) & 31) << 4));
            half8 a;
            #pragma unroll
            for (int j = 0; j < 4; ++j) {
                a[j]     = (_Float16)f0[j];
                a[j + 4] = (_Float16)f1[j];
            }
            af[s] = a;
        }

        // kick off next tile's DMA into the other buffer
        if (i + 1 < tpb)
            dma_quarter(x, (tile0 + i + 1) * 64 + 16 * w, &lds[(i + 1) & 1][w * 8192], lane);

        // ---- Phase A: z-GEMM (bias in acc init) + sigmoid -> packed cols 8t+n
        #pragma unroll
        for (int nt = 0; nt < 7; ++nt) {
            f32x4 acc = {bb[nt], bb[nt], bb[nt], bb[nt]};
            #pragma unroll
            for (int s = 0; s < 4; ++s)
                acc = __builtin_amdgcn_mfma_f32_16x16x32_f16(af[s], bf[nt][s], acc, 0, 0, 0);
            int node = 16 * nt + lm;
            int col  = node + ((node * 9363) >> 16);   // node + node/7 = 8t+n
            #pragma unroll
            for (int r = 0; r < 4; ++r) {
                float z  = acc[r];                     // C/D: row=4lq+r, col=lm
                float sg = __builtin_amdgcn_rcpf(1.0f + __expf(-z));
                *(_Float16*)(qcur + (4 * lq + r) * RSTR + col * 2) = (_Float16)sg;
            }
        }

        // ---- Phase B: leaf probabilities (wave-lockstep, reads before writes)
        // b128 gather: tree t=4g+tt occupies halves [8t..8t+7] = byte 16t,
        // 16B-aligned since RSTR=272=17*16. Element 7 (col 8t+7) is never
        // written by Phase A and never converted here.
        {
            const char* rowp = qcur + rg * RSTR;
            half8 hv[4];
            #pragma unroll
            for (int tt = 0; tt < 4; ++tt)
                hv[tt] = *(const half8*)(rowp + 64 * g + 16 * tt);
            half8 lv[4];
            #pragma unroll
            for (int tt = 0; tt < 4; ++tt) {
                float s0 = (float)hv[tt][0], s1 = (float)hv[tt][1], s2v = (float)hv[tt][2];
                float s3 = (float)hv[tt][3], s4 = (float)hv[tt][4], s5 = (float)hv[tt][5];
                float s6 = (float)hv[tt][6];
                float u1 = 1.f - s0, u2 = s0;
                float q1 = u1 * s1, q0 = u1 - q1;
                float q3 = u2 * s2v, q2 = u2 - q3;
                float L1 = q0 * s3, L0 = q0 - L1;
                float L3 = q1 * s4, L2 = q1 - L3;
                float L5 = q2 * s5, L4 = q2 - L5;
                float L7 = q3 * s6, L6 = q3 - L7;
                float m = (4 * g + tt < TREES) ? 1.f : 0.f;   // zero tree-15 slot
                half8 lv8;
                lv8[0] = (_Float16)(L0 * m); lv8[1] = (_Float16)(L1 * m);
                lv8[2] = (_Float16)(L2 * m); lv8[3] = (_Float16)(L3 * m);
                lv8[4] = (_Float16)(L4 * m); lv8[5] = (_Float16)(L5 * m);
                lv8[6] = (_Float16)(L6 * m); lv8[7] = (_Float16)(L7 * m);
                lv[tt] = lv8;
            }
            #pragma unroll
            for (int tt = 0; tt < 4; ++tt)
                *(half8*)(qcur + rg * RSTR + 64 * g + 16 * tt) = lv[tt];
        }

        // ---- Phase C: leaf x wbf MFMA -> out ----
        {
            half8 af2[4];
            #pragma unroll
            for (int s = 0; s < 4; ++s)
                af2[s] = *(const half8*)(qcur + lm * RSTR + 64 * s + 16 * lq);
            f32x4 a2 = {0.f, 0.f, 0.f, 0.f};
            #pragma unroll
            for (int s = 0; s < 4; ++s)
                a2 = __builtin_amdgcn_mfma_f32_16x16x32_f16(af2[s], wbf[s], a2, 0, 0, 0);
            if (lm < NCLS) {
                #pragma unroll
                for (int r = 0; r < 4; ++r)
                    out[(grow + 16 * w + 4 * lq + r) * NCLS + lm] = a2[r];
            }
        }
    }
}

// ---------------------------------------------------------------------------
extern "C" void kernel_launch(void* const* d_in, const int* in_sizes, int n_in,
                              void* d_out, int out_size, void* d_ws, size_t ws_size,
                              hipStream_t stream) {
    const float* x      = (const float*)d_in[0];
    const float* params = (const float*)d_in[1];
    float* out = (float*)d_out;

    const int batch = in_sizes[0] / IDIM;      // 262144
    const int tiles = batch / 64;              // 4096
    const int tpb   = tiles / NBLK;            // 8

    tree_main<<<NBLK, 256, 0, stream>>>(x, params, out, tpb);
}

// Round 2
// 203.083 us; speedup vs baseline: 1.4974x; 1.4974x over previous
//
#include <hip/hip_runtime.h>
#include <hip/hip_fp16.h>

// ---------------------------------------------------------------------------
// SoftDecisionTreeEnsemble: N_TREES=15, DEPTH=3, INPUT_DIM=128, N_CLASSES=10
// R4 = R2 (two-dispatch, proven 204.3us) + three register-pressure-neutral
// fixes. R3's single-dispatch weight materialization spilled (VGPR=128 with
// 128 resident weight VGPRs -> 217MB scratch writes, tree_main 190us). The
// prep kernel is load-bearing: packed-f16 wq/wbT lets bf/wbf sit resident as
// trivial half8 loads.
//  1. counted vmcnt(4) at tile top (peeled i==0): prev tile's 4 out-store
//     acks no longer serialize each tile (T4: never drain vmcnt in-loop).
//  2. Phase B: 28x ds_read_u16 (conflicted) -> 4x ds_read_b128
//     (RSTR=272=17*16: 16B-aligned, addr16=17*rg+4g ~2 lanes/col = free).
//  3. bias folded into MFMA accumulator init (kills 112 v_add per tile-lane).
// ---------------------------------------------------------------------------

typedef float    f32x4 __attribute__((ext_vector_type(4)));
typedef _Float16 half8 __attribute__((ext_vector_type(8)));

#define TREES      15
#define IDIM       128
#define NCLS       10
#define NINT       7
#define NLVS       8
#define PER_TREE   (NINT*IDIM + NINT + NLVS*NCLS)   // 983
#define NODES      (TREES*NINT)                     // 105
#define NPAD       112                              // 7 n-tiles of 16
#define KPAD       128                              // leaf K padded
#define RSTR       272                              // s/leaf row stride bytes (136 halves)
#define NBLK       512                              // 2 blocks/CU

// ---------------------------------------------------------------------------
// prep: wq[112][128] f16 (row g=7t+n, zero-padded), bq[112] f32 (zero-padded),
//       wbT[16][128] f16: wbT[c][8t+l] = softmax(leaf_logits[t][l])[c]*tw[t].
// Zero padding is load-bearing: padded nodes give z=0 -> sigmoid 0.5 ->
// garbage-free; padded leaf cols/classes contribute 0.
// ---------------------------------------------------------------------------
__global__ __launch_bounds__(256) void prep_kernel(const float* __restrict__ p,
                                                   _Float16* __restrict__ wq,
                                                   float* __restrict__ bq,
                                                   _Float16* __restrict__ wbT) {
    const int gid  = blockIdx.x * 256 + threadIdx.x;
    const int nthr = gridDim.x * 256;

    for (int i = gid; i < NPAD * IDIM; i += nthr) {
        int g = i >> 7, k = i & 127;
        float v = 0.f;
        if (g < NODES) {
            int t = g / NINT, n = g % NINT;
            v = p[t * PER_TREE + n * IDIM + k];
        }
        wq[i] = (_Float16)v;
    }
    for (int i = gid; i < NPAD; i += nthr) {
        float v = 0.f;
        if (i < NODES) {
            int t = i / NINT, n = i % NINT;
            v = p[t * PER_TREE + NINT * IDIM + n];
        }
        bq[i] = v;
    }
    const float* tl = p + TREES * PER_TREE;
    for (int i = gid; i < 16 * KPAD; i += nthr) {
        int c = i >> 7, k = i & 127;
        float v = 0.f;
        if (c < NCLS && k < TREES * NLVS) {
            int t = k >> 3, l = k & 7;
            const float* ll = p + t * PER_TREE + NINT * IDIM + NINT + l * NCLS;
            float mx = ll[0];
            #pragma unroll
            for (int j = 1; j < NCLS; ++j) mx = fmaxf(mx, ll[j]);
            float se = 0.f;
            #pragma unroll
            for (int j = 0; j < NCLS; ++j) se += __expf(ll[j] - mx);
            float lsm = __expf(ll[c] - mx) / se;

            float m2 = tl[0];
            #pragma unroll
            for (int j = 1; j < TREES; ++j) m2 = fmaxf(m2, tl[j]);
            float s2 = 0.f;
            #pragma unroll
            for (int j = 0; j < TREES; ++j) s2 += __expf(tl[j] - m2);
            float tw = __expf(tl[t] - m2) / s2;
            v = lsm * tw;
        }
        wbT[i] = (_Float16)v;
    }
}

// DMA one wave-quarter (16 rows x 512B) of an x tile into LDS, with per-row
// 16B-chunk rotation: row r chunk c16 stored at slot (c16 + r) & 31.
// LDS dest of global_load_lds is wave-uniform base + lane*16 (lane-linear),
// so the swizzle is applied on the *global source* side.
__device__ __forceinline__ void dma_quarter(const float* __restrict__ x,
                                            long grow0, char* qdst, int lane) {
    const int slot = lane & 31;
    #pragma unroll
    for (int it = 0; it < 8; ++it) {
        int r   = 2 * it + (lane >> 5);
        int c16 = (slot - r) & 31;
        const float* gp = x + (grow0 + r) * IDIM + c16 * 4;
        __builtin_amdgcn_global_load_lds(
            (const __attribute__((address_space(1))) void*)gp,
            (__attribute__((address_space(3))) void*)(qdst + it * 1024),
            16, 0, 0);
    }
}

// ---------------------------------------------------------------------------
__global__ __launch_bounds__(256, 2) void tree_main(const float* __restrict__ x,
                                                    const _Float16* __restrict__ wq,
                                                    const float* __restrict__ bq,
                                                    const _Float16* __restrict__ wbT,
                                                    float* __restrict__ out,
                                                    int tpb) {
    __shared__ __align__(16) char lds[2][32768];

    const int tid  = threadIdx.x;
    const int lane = tid & 63;
    const int w    = tid >> 6;        // wave id: owns rows 16w..16w+15 of tile
    const int lm   = lane & 15;
    const int lq   = lane >> 4;
    const int rg   = lane >> 2;       // Phase B row (0..15)
    const int g    = lane & 3;        // Phase B tree group

    const long tile0 = (long)blockIdx.x * tpb;

    // prime the pipeline: DMA tile 0
    dma_quarter(x, tile0 * 64 + 16 * w, &lds[0][w * 8192], lane);

    // resident weights: B-frags (7 n-tiles), biases, class weights.
    // Packed f16 -> plain half8 vector loads; keeps regalloc happy (R3 lesson).
    half8 bf[7][4];
    float bb[7];
    #pragma unroll
    for (int nt = 0; nt < 7; ++nt) {
        bb[nt] = bq[16 * nt + lm];
        #pragma unroll
        for (int s = 0; s < 4; ++s)
            bf[nt][s] = *reinterpret_cast<const half8*>(wq + (16 * nt + lm) * IDIM + 32 * s + 8 * lq);
    }
    half8 wbf[4];
    #pragma unroll
    for (int s = 0; s < 4; ++s)
        wbf[s] = *reinterpret_cast<const half8*>(wbT + lm * KPAD + 32 * s + 8 * lq);

    for (int i = 0; i < tpb; ++i) {
        char* qcur = &lds[i & 1][w * 8192];
        const long grow = (tile0 + i) * 64;      // global row of this tile

        // wait for own DMA (wave-private; no barrier needed).
        // i==0: vmcnt(0) (only the 8 primed loads + resident-weight loads).
        // i>=1: vmcnt(4) — outstanding = 8 loads(tile i, oldest) then 4
        //       stores(i-1); waiting to <=4 retires exactly the loads and
        //       lets the store-acks keep flying (T4).
        asm volatile("" ::: "memory");
        if (i == 0) __builtin_amdgcn_s_waitcnt(0x0F70);
        else        __builtin_amdgcn_s_waitcnt(0x0F74);
        asm volatile("" ::: "memory");

        // ---- A-fragment gather from swizzled LDS + cvt to f16 ----
        half8 af[4];
        #pragma unroll
        for (int s = 0; s < 4; ++s) {
            int cc = 8 * s + 2 * lq;
            f32x4 f0 = *(const f32x4*)(qcur + lm * 512 + (((cc     + lm) & 31) << 4));
            f32x4 f1 = *(const f32x4*)(qcur + lm * 512 + (((cc + 1 + lm) & 31) << 4));
            half8 a;
            #pragma unroll
            for (int j = 0; j < 4; ++j) {
                a[j]     = (_Float16)f0[j];
                a[j + 4] = (_Float16)f1[j];
            }
            af[s] = a;
        }

        // kick off next tile's DMA into the other buffer
        if (i + 1 < tpb)
            dma_quarter(x, (tile0 + i + 1) * 64 + 16 * w, &lds[(i + 1) & 1][w * 8192], lane);

        // ---- Phase A: z-GEMM (bias in acc init) + sigmoid -> packed cols 8t+n
        #pragma unroll
        for (int nt = 0; nt < 7; ++nt) {
            f32x4 acc = {bb[nt], bb[nt], bb[nt], bb[nt]};
            #pragma unroll
            for (int s = 0; s < 4; ++s)
                acc = __builtin_amdgcn_mfma_f32_16x16x32_f16(af[s], bf[nt][s], acc, 0, 0, 0);
            int node = 16 * nt + lm;
            int col  = node + ((node * 9363) >> 16);   // node + node/7 = 8t+n
            #pragma unroll
            for (int r = 0; r < 4; ++r) {
                float z  = acc[r];                     // C/D: row=4lq+r, col=lm
                float sg = __builtin_amdgcn_rcpf(1.0f + __expf(-z));
                *(_Float16*)(qcur + (4 * lq + r) * RSTR + col * 2) = (_Float16)sg;
            }
        }

        // ---- Phase B: leaf probabilities (wave-lockstep, reads before writes)
        // b128 gather: tree t=4g+tt occupies halves [8t..8t+7] = byte 16t,
        // 16B-aligned since RSTR=272=17*16. Element 7 (col 8t+7) is never
        // written by Phase A and never used here.
        {
            const char* rowp = qcur + rg * RSTR;
            half8 hv[4];
            #pragma unroll
            for (int tt = 0; tt < 4; ++tt)
                hv[tt] = *(const half8*)(rowp + 64 * g + 16 * tt);
            half8 lv[4];
            #pragma unroll
            for (int tt = 0; tt < 4; ++tt) {
                float s0 = (float)hv[tt][0], s1 = (float)hv[tt][1], s2v = (float)hv[tt][2];
                float s3 = (float)hv[tt][3], s4 = (float)hv[tt][4], s5 = (float)hv[tt][5];
                float s6 = (float)hv[tt][6];
                float u1 = 1.f - s0, u2 = s0;
                float q1 = u1 * s1, q0 = u1 - q1;
                float q3 = u2 * s2v, q2 = u2 - q3;
                float L1 = q0 * s3, L0 = q0 - L1;
                float L3 = q1 * s4, L2 = q1 - L3;
                float L5 = q2 * s5, L4 = q2 - L5;
                float L7 = q3 * s6, L6 = q3 - L7;
                float m = (4 * g + tt < TREES) ? 1.f : 0.f;   // zero tree-15 slot
                half8 lv8;
                lv8[0] = (_Float16)(L0 * m); lv8[1] = (_Float16)(L1 * m);
                lv8[2] = (_Float16)(L2 * m); lv8[3] = (_Float16)(L3 * m);
                lv8[4] = (_Float16)(L4 * m); lv8[5] = (_Float16)(L5 * m);
                lv8[6] = (_Float16)(L6 * m); lv8[7] = (_Float16)(L7 * m);
                lv[tt] = lv8;
            }
            #pragma unroll
            for (int tt = 0; tt < 4; ++tt)
                *(half8*)(qcur + rg * RSTR + 64 * g + 16 * tt) = lv[tt];
        }

        // ---- Phase C: leaf x wbT MFMA -> out ----
        {
            half8 af2[4];
            #pragma unroll
            for (int s = 0; s < 4; ++s)
                af2[s] = *(const half8*)(qcur + lm * RSTR + 64 * s + 16 * lq);
            f32x4 a2 = {0.f, 0.f, 0.f, 0.f};
            #pragma unroll
            for (int s = 0; s < 4; ++s)
                a2 = __builtin_amdgcn_mfma_f32_16x16x32_f16(af2[s], wbf[s], a2, 0, 0, 0);
            if (lm < NCLS) {
                #pragma unroll
                for (int r = 0; r < 4; ++r)
                    out[(grow + 16 * w + 4 * lq + r) * NCLS + lm] = a2[r];
            }
        }
    }
}

// ---------------------------------------------------------------------------
extern "C" void kernel_launch(void* const* d_in, const int* in_sizes, int n_in,
                              void* d_out, int out_size, void* d_ws, size_t ws_size,
                              hipStream_t stream) {
    const float* x      = (const float*)d_in[0];
    const float* params = (const float*)d_in[1];
    float* out = (float*)d_out;

    _Float16* wq  = (_Float16*)d_ws;                             // 28672 B
    float*    bq  = (float*)((char*)d_ws + NPAD * IDIM * 2);     // 448 B
    _Float16* wbT = (_Float16*)((char*)bq + NPAD * 4);           // 4096 B

    const int batch = in_sizes[0] / IDIM;      // 262144
    const int tiles = batch / 64;              // 4096
    const int tpb   = tiles / NBLK;            // 8

    prep_kernel<<<8, 256, 0, stream>>>(params, wq, bq, wbT);
    tree_main<<<NBLK, 256, 0, stream>>>(x, wq, bq, wbT, out, tpb);
}

// Round 3
// 202.145 us; speedup vs baseline: 1.5043x; 1.0046x over previous
//
#include <hip/hip_runtime.h>
#include <hip/hip_fp16.h>

// ---------------------------------------------------------------------------
// SoftDecisionTreeEnsemble: N_TREES=15, DEPTH=3, INPUT_DIM=128, N_CLASSES=10
// R5 = R4 (203.1us) + latency-depth attack. tree_main reconstructed at ~72us
// vs 21us HBM floor (27% BW, matches R3's measured 27%): latency-bound.
//  1. 2-tiles-ahead DMA: tile i+2 is DMA'd into the SAME buffer tile i just
//     vacated (after Phase C gather). In-flight doubles to 16KB/wave
//     (128KB/CU) at zero LDS/VGPR cost. Counted waits: i==1 vmcnt(12),
//     steady vmcnt(16), last vmcnt(8) (in-order vmcnt accounting).
//  2. rotation swizzle dropped: it split 64B lane-quads across cache lines
//     for 3/4 of rows (2x request count); the A-gather ds_read_b128 is a
//     1KB/instr full-wave read (8 LDS phases regardless of bank mapping),
//     so the swizzle bought nothing. Linear source / linear image / linear
//     gather.
//  3. explicit vmcnt(0) after weight loads (pre-loop) so the compiler's
//     waitcnt pass sees weights resolved and emits no in-loop vm waits.
// ---------------------------------------------------------------------------

typedef float    f32x4 __attribute__((ext_vector_type(4)));
typedef _Float16 half8 __attribute__((ext_vector_type(8)));

#define TREES      15
#define IDIM       128
#define NCLS       10
#define NINT       7
#define NLVS       8
#define PER_TREE   (NINT*IDIM + NINT + NLVS*NCLS)   // 983
#define NODES      (TREES*NINT)                     // 105
#define NPAD       112                              // 7 n-tiles of 16
#define KPAD       128                              // leaf K padded
#define RSTR       272                              // s/leaf row stride bytes (136 halves)
#define NBLK       512                              // 2 blocks/CU

// ---------------------------------------------------------------------------
// prep: wq[112][128] f16 (row g=7t+n, zero-padded), bq[112] f32 (zero-padded),
//       wbT[16][128] f16: wbT[c][8t+l] = softmax(leaf_logits[t][l])[c]*tw[t].
// Zero padding is load-bearing: padded nodes give z=0 -> sigmoid 0.5 ->
// garbage-free; padded leaf cols/classes contribute 0.
// ---------------------------------------------------------------------------
__global__ __launch_bounds__(256) void prep_kernel(const float* __restrict__ p,
                                                   _Float16* __restrict__ wq,
                                                   float* __restrict__ bq,
                                                   _Float16* __restrict__ wbT) {
    const int gid  = blockIdx.x * 256 + threadIdx.x;
    const int nthr = gridDim.x * 256;

    for (int i = gid; i < NPAD * IDIM; i += nthr) {
        int g = i >> 7, k = i & 127;
        float v = 0.f;
        if (g < NODES) {
            int t = g / NINT, n = g % NINT;
            v = p[t * PER_TREE + n * IDIM + k];
        }
        wq[i] = (_Float16)v;
    }
    for (int i = gid; i < NPAD; i += nthr) {
        float v = 0.f;
        if (i < NODES) {
            int t = i / NINT, n = i % NINT;
            v = p[t * PER_TREE + NINT * IDIM + n];
        }
        bq[i] = v;
    }
    const float* tl = p + TREES * PER_TREE;
    for (int i = gid; i < 16 * KPAD; i += nthr) {
        int c = i >> 7, k = i & 127;
        float v = 0.f;
        if (c < NCLS && k < TREES * NLVS) {
            int t = k >> 3, l = k & 7;
            const float* ll = p + t * PER_TREE + NINT * IDIM + NINT + l * NCLS;
            float mx = ll[0];
            #pragma unroll
            for (int j = 1; j < NCLS; ++j) mx = fmaxf(mx, ll[j]);
            float se = 0.f;
            #pragma unroll
            for (int j = 0; j < NCLS; ++j) se += __expf(ll[j] - mx);
            float lsm = __expf(ll[c] - mx) / se;

            float m2 = tl[0];
            #pragma unroll
            for (int j = 1; j < TREES; ++j) m2 = fmaxf(m2, tl[j]);
            float s2 = 0.f;
            #pragma unroll
            for (int j = 0; j < TREES; ++j) s2 += __expf(tl[j] - m2);
            float tw = __expf(tl[t] - m2) / s2;
            v = lsm * tw;
        }
        wbT[i] = (_Float16)v;
    }
}

// DMA one wave-quarter (16 rows x 512B) of an x tile into LDS, LINEAR:
// lanes 0-31 read one contiguous 512B row (perfect coalescing), lanes 32-63
// the next row. LDS dest is lane-linear -> image is row-major [16][512B].
__device__ __forceinline__ void dma_quarter(const float* __restrict__ x,
                                            long grow0, char* qdst, int lane) {
    #pragma unroll
    for (int it = 0; it < 8; ++it) {
        int r = 2 * it + (lane >> 5);
        const float* gp = x + (grow0 + r) * IDIM + (lane & 31) * 4;
        __builtin_amdgcn_global_load_lds(
            (const __attribute__((address_space(1))) void*)gp,
            (__attribute__((address_space(3))) void*)(qdst + it * 1024),
            16, 0, 0);
    }
}

// ---------------------------------------------------------------------------
__global__ __launch_bounds__(256, 2) void tree_main(const float* __restrict__ x,
                                                    const _Float16* __restrict__ wq,
                                                    const float* __restrict__ bq,
                                                    const _Float16* __restrict__ wbT,
                                                    float* __restrict__ out,
                                                    int tpb) {
    __shared__ __align__(16) char lds[2][32768];

    const int tid  = threadIdx.x;
    const int lane = tid & 63;
    const int w    = tid >> 6;        // wave id: owns rows 16w..16w+15 of tile
    const int lm   = lane & 15;
    const int lq   = lane >> 4;
    const int rg   = lane >> 2;       // Phase B row (0..15)
    const int g    = lane & 3;        // Phase B tree group

    const long tile0 = (long)blockIdx.x * tpb;

    // prime: DMA tile 0 (overlaps the weight loads below)
    dma_quarter(x, tile0 * 64 + 16 * w, &lds[0][w * 8192], lane);

    // resident weights: B-frags (7 n-tiles), biases, class weights.
    // Packed f16 -> plain half8 vector loads; keeps regalloc happy (R3 lesson).
    half8 bf[7][4];
    float bb[7];
    #pragma unroll
    for (int nt = 0; nt < 7; ++nt) {
        bb[nt] = bq[16 * nt + lm];
        #pragma unroll
        for (int s = 0; s < 4; ++s)
            bf[nt][s] = *reinterpret_cast<const half8*>(wq + (16 * nt + lm) * IDIM + 32 * s + 8 * lq);
    }
    half8 wbf[4];
    #pragma unroll
    for (int s = 0; s < 4; ++s)
        wbf[s] = *reinterpret_cast<const half8*>(wbT + lm * KPAD + 32 * s + 8 * lq);

    // drain tile-0 DMA + all weight loads ONCE, so the compiler's waitcnt
    // pass sees weights resolved (no conservative in-loop vm waits), then
    // prime the second prefetch slot.
    asm volatile("" ::: "memory");
    __builtin_amdgcn_s_waitcnt(0x0F70);           // vmcnt(0)
    asm volatile("" ::: "memory");
    if (tpb > 1)
        dma_quarter(x, (tile0 + 1) * 64 + 16 * w, &lds[1][w * 8192], lane);

    for (int i = 0; i < tpb; ++i) {
        char* qcur = &lds[i & 1][w * 8192];
        const long grow = (tile0 + i) * 64;      // global row of this tile

        // Counted wait for THIS tile's DMA (wave-private; no barrier).
        // In-order vm queue at top of iter i (D=8 DMA loads, s=4 stores):
        //   i==0 : [D1]                        -> tile 0 already drained above
        //   i==1 : [D1, D2, st0]               -> need D1: vmcnt(12)
        //   steady: [Di, st(i-2), Di+1, st(i-1)]-> need Di: vmcnt(16)
        //   last  : [Dn-1, st(n-3), st(n-2)]   -> need Dn-1: vmcnt(8)
        asm volatile("" ::: "memory");
        if (i == 1)                __builtin_amdgcn_s_waitcnt(0x0F7C); // vmcnt(12)
        else if (i >= 2 && i < tpb - 1)
                                   __builtin_amdgcn_s_waitcnt(0x4F70); // vmcnt(16)
        else if (i == tpb - 1 && i >= 2)
                                   __builtin_amdgcn_s_waitcnt(0x0F78); // vmcnt(8)
        asm volatile("" ::: "memory");

        // ---- A-fragment gather from LINEAR LDS image + cvt to f16 ----
        half8 af[4];
        #pragma unroll
        for (int s = 0; s < 4; ++s) {
            int cc = 8 * s + 2 * lq;
            f32x4 f0 = *(const f32x4*)(qcur + lm * 512 + (cc     << 4));
            f32x4 f1 = *(const f32x4*)(qcur + lm * 512 + ((cc + 1) << 4));
            half8 a;
            #pragma unroll
            for (int j = 0; j < 4; ++j) {
                a[j]     = (_Float16)f0[j];
                a[j + 4] = (_Float16)f1[j];
            }
            af[s] = a;
        }

        // ---- Phase A: z-GEMM (bias in acc init) + sigmoid -> packed cols 8t+n
        #pragma unroll
        for (int nt = 0; nt < 7; ++nt) {
            f32x4 acc = {bb[nt], bb[nt], bb[nt], bb[nt]};
            #pragma unroll
            for (int s = 0; s < 4; ++s)
                acc = __builtin_amdgcn_mfma_f32_16x16x32_f16(af[s], bf[nt][s], acc, 0, 0, 0);
            int node = 16 * nt + lm;
            int col  = node + ((node * 9363) >> 16);   // node + node/7 = 8t+n
            #pragma unroll
            for (int r = 0; r < 4; ++r) {
                float z  = acc[r];                     // C/D: row=4lq+r, col=lm
                float sg = __builtin_amdgcn_rcpf(1.0f + __expf(-z));
                *(_Float16*)(qcur + (4 * lq + r) * RSTR + col * 2) = (_Float16)sg;
            }
        }

        // ---- Phase B: leaf probabilities (wave-lockstep, reads before writes)
        {
            const char* rowp = qcur + rg * RSTR;
            half8 hv[4];
            #pragma unroll
            for (int tt = 0; tt < 4; ++tt)
                hv[tt] = *(const half8*)(rowp + 64 * g + 16 * tt);
            half8 lv[4];
            #pragma unroll
            for (int tt = 0; tt < 4; ++tt) {
                float s0 = (float)hv[tt][0], s1 = (float)hv[tt][1], s2v = (float)hv[tt][2];
                float s3 = (float)hv[tt][3], s4 = (float)hv[tt][4], s5 = (float)hv[tt][5];
                float s6 = (float)hv[tt][6];
                float u1 = 1.f - s0, u2 = s0;
                float q1 = u1 * s1, q0 = u1 - q1;
                float q3 = u2 * s2v, q2 = u2 - q3;
                float L1 = q0 * s3, L0 = q0 - L1;
                float L3 = q1 * s4, L2 = q1 - L3;
                float L5 = q2 * s5, L4 = q2 - L5;
                float L7 = q3 * s6, L6 = q3 - L7;
                float m = (4 * g + tt < TREES) ? 1.f : 0.f;   // zero tree-15 slot
                half8 lv8;
                lv8[0] = (_Float16)(L0 * m); lv8[1] = (_Float16)(L1 * m);
                lv8[2] = (_Float16)(L2 * m); lv8[3] = (_Float16)(L3 * m);
                lv8[4] = (_Float16)(L4 * m); lv8[5] = (_Float16)(L5 * m);
                lv8[6] = (_Float16)(L6 * m); lv8[7] = (_Float16)(L7 * m);
                lv[tt] = lv8;
            }
            #pragma unroll
            for (int tt = 0; tt < 4; ++tt)
                *(half8*)(qcur + rg * RSTR + 64 * g + 16 * tt) = lv[tt];
        }

        // ---- Phase C: leaf x wbT MFMA -> out ----
        {
            half8 af2[4];
            #pragma unroll
            for (int s = 0; s < 4; ++s)
                af2[s] = *(const half8*)(qcur + lm * RSTR + 64 * s + 16 * lq);
            f32x4 a2 = {0.f, 0.f, 0.f, 0.f};
            #pragma unroll
            for (int s = 0; s < 4; ++s)
                a2 = __builtin_amdgcn_mfma_f32_16x16x32_f16(af2[s], wbf[s], a2, 0, 0, 0);

            // qcur fully consumed (af2 gather waited by the MFMA's lgkm):
            // DMA tile i+2 into this same buffer. Fences pin the issue point
            // between the Phase-C reads and the output stores so the vm
            // queue order is [.., D(i+2), st(i)].
            asm volatile("" ::: "memory");
            if (i + 2 < tpb)
                dma_quarter(x, (tile0 + i + 2) * 64 + 16 * w, qcur, lane);
            asm volatile("" ::: "memory");

            if (lm < NCLS) {
                #pragma unroll
                for (int r = 0; r < 4; ++r)
                    out[(grow + 16 * w + 4 * lq + r) * NCLS + lm] = a2[r];
            }
        }
    }
}

// ---------------------------------------------------------------------------
extern "C" void kernel_launch(void* const* d_in, const int* in_sizes, int n_in,
                              void* d_out, int out_size, void* d_ws, size_t ws_size,
                              hipStream_t stream) {
    const float* x      = (const float*)d_in[0];
    const float* params = (const float*)d_in[1];
    float* out = (float*)d_out;

    _Float16* wq  = (_Float16*)d_ws;                             // 28672 B
    float*    bq  = (float*)((char*)d_ws + NPAD * IDIM * 2);     // 448 B
    _Float16* wbT = (_Float16*)((char*)bq + NPAD * 4);           // 4096 B

    const int batch = in_sizes[0] / IDIM;      // 262144
    const int tiles = batch / 64;              // 4096
    const int tpb   = tiles / NBLK;            // 8

    prep_kernel<<<8, 256, 0, stream>>>(params, wq, bq, wbT);
    tree_main<<<NBLK, 256, 0, stream>>>(x, wq, bq, wbT, out, tpb);
}